// Round 1
// 363.128 us; speedup vs baseline: 1.0151x; 1.0151x over previous
//
#include <hip/hip_runtime.h>

#define BLOCK 256
#define RPB   128          // rows per block: 64 quads x 2 rows
#define WPS   260          // Wp LDS row stride (floats): 260%32=4 -> quad lanes on distinct banks
#define WS    36           // 32x32 weight LDS row stride (floats): 36%32=4 -> conflict-free b128

#define DOT4(A_, W_) ((A_).x*(W_).x + (A_).y*(W_).y + (A_).z*(W_).z + (A_).w*(W_).w)

// out[d] = sum_j W[d][j] * in[j] for this lane's 8 outputs d = q+4e, two rows sharing
// each weight read. W is stored with permuted columns: col j at (j&3)*8 + (j>>2), so the
// slice held by lane (q^p) (elements j = (q^p)+4*j') is contiguous -> float4 reads.
__device__ __forceinline__ void matvec32(const float* __restrict__ WL, const int q,
                                         const float* __restrict__ in0, const float* __restrict__ in1,
                                         float* __restrict__ out0, float* __restrict__ out1)
{
    #pragma unroll
    for (int e = 0; e < 8; ++e) { out0[e] = 0.f; out1[e] = 0.f; }
    #pragma unroll
    for (int p = 0; p < 4; ++p) {
        float xs0[8], xs1[8];
        #pragma unroll
        for (int j = 0; j < 8; ++j) {       // quad_perm DPP, VALU pipe (compile-time mask)
            xs0[j] = (p == 0) ? in0[j] : __shfl_xor(in0[j], p);
            xs1[j] = (p == 0) ? in1[j] : __shfl_xor(in1[j], p);
        }
        const float* wb = WL + q * WS + (q ^ p) * 8;
        #pragma unroll
        for (int e = 0; e < 8; ++e) {       // bank = 4q+16e+8(q^p)+... -> distinct across quad
            float4 w0 = *(const float4*)(wb + e * (4 * WS));
            float4 w1 = *(const float4*)(wb + e * (4 * WS) + 4);
            out0[e] += w0.x*xs0[0] + w0.y*xs0[1] + w0.z*xs0[2] + w0.w*xs0[3]
                     + w1.x*xs0[4] + w1.y*xs0[5] + w1.z*xs0[6] + w1.w*xs0[7];
            out1[e] += w0.x*xs1[0] + w0.y*xs1[1] + w0.z*xs1[2] + w0.w*xs1[3]
                     + w1.x*xs1[4] + w1.y*xs1[5] + w1.z*xs1[6] + w1.w*xs1[7];
        }
    }
}

__launch_bounds__(BLOCK, 2)
__global__ void msfe_kernel(
    const float* __restrict__ f1, const float* __restrict__ f4, const float* __restrict__ fD,
    const float* __restrict__ Wp, const float* __restrict__ bp,
    const float* __restrict__ ln_g, const float* __restrict__ ln_b,
    const float* __restrict__ Wq, const float* __restrict__ bq,
    const float* __restrict__ Wk, const float* __restrict__ bk,
    const float* __restrict__ Wv, const float* __restrict__ bv,
    const float* __restrict__ Wo1, const float* __restrict__ bo1,
    const float* __restrict__ Wo2, const float* __restrict__ bo2,
    float* __restrict__ out, int nRows)
{
    __shared__ float Wp_l[32 * WPS];                       // 33.3 KB, padded stride
    __shared__ float A_l[32 * WS];                         // Wq^T Wk / sqrt(D), permuted cols
    __shared__ float Wv_l[32 * WS], Wo1_l[32 * WS], Wo2_l[32 * WS];  // permuted cols
    __shared__ float bp_l[32], g_l[32], b_l[32], u_l[32], v_l[32];
    __shared__ float bv_l[32], bo1_l[32], bo2_l[32];
    __shared__ float c_l;

    const int tid = threadIdx.x;

    // ---- stage Wp: [32][256] -> stride-260 rows (coalesced float4) ----
    #pragma unroll
    for (int i = 0; i < 8; ++i) {
        int idx = tid + i * BLOCK;                 // float4 index 0..2047
        int d = idx >> 6, k4 = idx & 63;
        *(float4*)&Wp_l[d * WPS + 4 * k4] = ((const float4*)Wp)[idx];
    }
    // ---- stage Wv/Wo1/Wo2 with permuted columns: elem m of float4 j4 -> col' m*8+j4 ----
    {
        int d = tid >> 3, j4 = tid & 7;
        float4 wv = ((const float4*)Wv )[tid];
        float4 w1 = ((const float4*)Wo1)[tid];
        float4 w2 = ((const float4*)Wo2)[tid];
        float* pv = &Wv_l [d * WS + j4];
        float* p1 = &Wo1_l[d * WS + j4];
        float* p2 = &Wo2_l[d * WS + j4];
        pv[0] = wv.x; pv[8] = wv.y; pv[16] = wv.z; pv[24] = wv.w;
        p1[0] = w1.x; p1[8] = w1.y; p1[16] = w1.z; p1[24] = w1.w;
        p2[0] = w2.x; p2[8] = w2.y; p2[16] = w2.z; p2[24] = w2.w;
    }
    if (tid < 32) {
        bp_l[tid] = bp[tid]; g_l[tid] = ln_g[tid]; b_l[tid] = ln_b[tid];
        bv_l[tid] = bv[tid]; bo1_l[tid] = bo1[tid]; bo2_l[tid] = bo2[tid];
    }
    const float isq = 0.17677669529663688f;  // 1/sqrt(32)
    // ---- A = Wq^T Wk * isq (permuted cols), from global (L2-resident) ----
    {
        int a = tid >> 3, b4 = tid & 7;
        float s0 = 0.f, s1 = 0.f, s2 = 0.f, s3 = 0.f;
        #pragma unroll 8
        for (int d = 0; d < 32; ++d) {
            float  wq = Wq[d * 32 + a];
            float4 wk = *(const float4*)&Wk[d * 32 + 4 * b4];
            s0 += wq * wk.x; s1 += wq * wk.y; s2 += wq * wk.z; s3 += wq * wk.w;
        }
        float* pa = &A_l[a * WS + b4];
        pa[0] = s0 * isq; pa[8] = s1 * isq; pa[16] = s2 * isq; pa[24] = s3 * isq;
    }
    if (tid < 32) {
        float s = 0.f;
        #pragma unroll 8
        for (int d = 0; d < 32; ++d) s += bq[d] * Wk[d * 32 + tid];
        u_l[tid] = s * isq;
    } else if (tid < 64) {
        int a = tid - 32; float s = 0.f;
        #pragma unroll 8
        for (int d = 0; d < 32; ++d) s += Wq[d * 32 + a] * bk[d];
        v_l[a] = s * isq;
    } else if (tid == 64) {
        float s = 0.f;
        #pragma unroll 8
        for (int d = 0; d < 32; ++d) s += bq[d] * bk[d];
        c_l = s * isq;
    }
    __syncthreads();

    // ---- lane mapping: quad q owns interleaved outputs d = q + 4e; 2 rows per lane ----
    const int q  = tid & 3;
    const int r0 = blockIdx.x * RPB + 2 * (tid >> 2);
    if (r0 >= nRows) return;                       // whole quad exits together
    const int r1 = (r0 + 1 < nRows) ? r0 + 1 : nRows - 1;   // clamp loads at tail

    const float* pr[2][3];
    pr[0][0] = f1 + (size_t)r0 * 256; pr[0][1] = f4 + (size_t)r0 * 256; pr[0][2] = fD + (size_t)r0 * 256;
    pr[1][0] = f1 + (size_t)r1 * 256; pr[1][1] = f4 + (size_t)r1 * 256; pr[1][2] = fD + (size_t)r1 * 256;

    // ---- Phase A: full-K projection, 8 outputs per lane, 2 rows, 3 streams ----
    float acc[2][3][8];
    #pragma unroll
    for (int h = 0; h < 2; ++h)
        #pragma unroll
        for (int s = 0; s < 3; ++s)
            #pragma unroll
            for (int e = 0; e < 8; ++e) acc[h][s][e] = 0.f;

    float4 nA[2][3], nB[2][3];
    #pragma unroll
    for (int h = 0; h < 2; ++h)
        #pragma unroll
        for (int s = 0; s < 3; ++s) {
            nA[h][s] = *(const float4*)(pr[h][s]);
            nB[h][s] = *(const float4*)(pr[h][s] + 4);
        }

    const float* wbase = &Wp_l[q * WPS];

    #pragma unroll 1
    for (int kc = 0; kc < 256; kc += 8) {
        float4 cA[2][3], cB[2][3];
        #pragma unroll
        for (int h = 0; h < 2; ++h)
            #pragma unroll
            for (int s = 0; s < 3; ++s) { cA[h][s] = nA[h][s]; cB[h][s] = nB[h][s]; }
        const int kn = (kc + 8 < 256) ? kc + 8 : kc;     // last iter reloads (L1 hit)
        #pragma unroll
        for (int h = 0; h < 2; ++h)
            #pragma unroll
            for (int s = 0; s < 3; ++s) {
                nA[h][s] = *(const float4*)(pr[h][s] + kn);
                nB[h][s] = *(const float4*)(pr[h][s] + kn + 4);
            }
        #pragma unroll
        for (int e = 0; e < 8; ++e) {                    // d = q+4e -> conflict-free b128
            float4 w0 = *(const float4*)(wbase + e * (4 * WPS) + kc);
            float4 w1 = *(const float4*)(wbase + e * (4 * WPS) + kc + 4);
            #pragma unroll
            for (int h = 0; h < 2; ++h)
                #pragma unroll
                for (int s = 0; s < 3; ++s)
                    acc[h][s][e] += DOT4(cA[h][s], w0) + DOT4(cB[h][s], w1);
        }
    }

    // ---- bias + ReLU + LayerNorm (quad reduction over 32 dims) ----
    float Xh[2][3][8];
    float bpe[8], ge[8], be[8];
    #pragma unroll
    for (int e = 0; e < 8; ++e) { bpe[e] = bp_l[q + 4*e]; ge[e] = g_l[q + 4*e]; be[e] = b_l[q + 4*e]; }
    #pragma unroll
    for (int h = 0; h < 2; ++h)
        #pragma unroll
        for (int s = 0; s < 3; ++s) {
            float fe[8]; float sm = 0.f, sq = 0.f;
            #pragma unroll
            for (int e = 0; e < 8; ++e) {
                float t = fmaxf(acc[h][s][e] + bpe[e], 0.f);
                fe[e] = t; sm += t; sq += t * t;
            }
            sm += __shfl_xor(sm, 1); sm += __shfl_xor(sm, 2);
            sq += __shfl_xor(sq, 1); sq += __shfl_xor(sq, 2);
            float mu  = sm * 0.03125f;
            float var = sq * 0.03125f - mu * mu;
            float inv = rsqrtf(var + 1e-5f);
            #pragma unroll
            for (int e = 0; e < 8; ++e)
                Xh[h][s][e] = ge[e] * (fe[e] - mu) * inv + be[e];
        }

    // ---- scores sc[s][t] = X_s^T A X_t + u.X_t + v.X_s + c ----
    float uX[2][3], vX[2][3];
    {
        float uq[8], vq[8];
        #pragma unroll
        for (int e = 0; e < 8; ++e) { uq[e] = u_l[q + 4*e]; vq[e] = v_l[q + 4*e]; }
        #pragma unroll
        for (int h = 0; h < 2; ++h)
            #pragma unroll
            for (int t = 0; t < 3; ++t) {
                float us = 0.f, vs = 0.f;
                #pragma unroll
                for (int e = 0; e < 8; ++e) { us += uq[e] * Xh[h][t][e]; vs += vq[e] * Xh[h][t][e]; }
                us += __shfl_xor(us, 1); us += __shfl_xor(us, 2);
                vs += __shfl_xor(vs, 1); vs += __shfl_xor(vs, 2);
                uX[h][t] = us; vX[h][t] = vs;
            }
    }

    float sc[2][9];
    #pragma unroll
    for (int t = 0; t < 3; ++t) {
        float y0[8], y1[8];
        #pragma unroll
        for (int e = 0; e < 8; ++e) { y0[e] = 0.f; y1[e] = 0.f; }
        #pragma unroll
        for (int p = 0; p < 4; ++p) {
            float xs0[8], xs1[8];
            #pragma unroll
            for (int j = 0; j < 8; ++j) {
                xs0[j] = (p == 0) ? Xh[0][t][j] : __shfl_xor(Xh[0][t][j], p);
                xs1[j] = (p == 0) ? Xh[1][t][j] : __shfl_xor(Xh[1][t][j], p);
            }
            const float* ab = &A_l[q * WS + (q ^ p) * 8];
            #pragma unroll
            for (int e = 0; e < 8; ++e) {
                float4 a0 = *(const float4*)(ab + e * (4 * WS));
                float4 a1 = *(const float4*)(ab + e * (4 * WS) + 4);
                y0[e] += a0.x*xs0[0] + a0.y*xs0[1] + a0.z*xs0[2] + a0.w*xs0[3]
                       + a1.x*xs0[4] + a1.y*xs0[5] + a1.z*xs0[6] + a1.w*xs0[7];
                y1[e] += a0.x*xs1[0] + a0.y*xs1[1] + a0.z*xs1[2] + a0.w*xs1[3]
                       + a1.x*xs1[4] + a1.y*xs1[5] + a1.z*xs1[6] + a1.w*xs1[7];
            }
        }
        #pragma unroll
        for (int s = 0; s < 3; ++s) {
            float d0 = 0.f, d1 = 0.f;
            #pragma unroll
            for (int e = 0; e < 8; ++e) { d0 += Xh[0][s][e] * y0[e]; d1 += Xh[1][s][e] * y1[e]; }
            sc[0][s * 3 + t] = d0; sc[1][s * 3 + t] = d1;
        }
    }
    #pragma unroll
    for (int h = 0; h < 2; ++h)
        #pragma unroll
        for (int s = 0; s < 3; ++s)
            #pragma unroll
            for (int t = 0; t < 3; ++t) {
                float pv = sc[h][s * 3 + t];
                pv += __shfl_xor(pv, 1); pv += __shfl_xor(pv, 2);
                sc[h][s * 3 + t] = pv + uX[h][t] + vX[h][s] + c_l;
            }

    // ---- softmax rows; fold V through xb = sum_t g_t X_t (rows sum to 1 -> bias folds) ----
    float xb[2][8];
    #pragma unroll
    for (int h = 0; h < 2; ++h) {
        float g0 = 0.f, g1 = 0.f, g2 = 0.f;
        #pragma unroll
        for (int s = 0; s < 3; ++s) {
            float a0 = sc[h][s*3+0], a1 = sc[h][s*3+1], a2 = sc[h][s*3+2];
            float m  = fmaxf(a0, fmaxf(a1, a2));
            float e0 = __expf(a0 - m), e1 = __expf(a1 - m), e2 = __expf(a2 - m);
            float r  = 1.f / (e0 + e1 + e2);
            g0 += e0 * r; g1 += e1 * r; g2 += e2 * r;
        }
        g0 *= (1.f/3.f); g1 *= (1.f/3.f); g2 *= (1.f/3.f);
        #pragma unroll
        for (int e = 0; e < 8; ++e)
            xb[h][e] = g0 * Xh[h][0][e] + g1 * Xh[h][1][e] + g2 * Xh[h][2][e];
    }

    // ---- pooled = Wv xb + bv ; h1 = relu(Wo1 pooled + bo1) ; out = Wo2 h1 + bo2 + pooled ----
    float t0[8], t1[8], ph0[8], ph1[8];
    matvec32(Wv_l, q, xb[0], xb[1], t0, t1);
    #pragma unroll
    for (int e = 0; e < 8; ++e) {
        float bve = bv_l[q + 4*e];
        ph0[e] = t0[e] + bve; ph1[e] = t1[e] + bve;
    }
    float hh0[8], hh1[8];
    matvec32(Wo1_l, q, ph0, ph1, t0, t1);
    #pragma unroll
    for (int e = 0; e < 8; ++e) {
        float b1e = bo1_l[q + 4*e];
        hh0[e] = fmaxf(t0[e] + b1e, 0.f); hh1[e] = fmaxf(t1[e] + b1e, 0.f);
    }
    matvec32(Wo2_l, q, hh0, hh1, t0, t1);

    float* o0 = out + (size_t)r0 * 32 + q;
    float* o1 = out + (size_t)(r0 + 1) * 32 + q;
    const bool w1ok = (r0 + 1 < nRows);
    #pragma unroll
    for (int e = 0; e < 8; ++e) {
        float b2e = bo2_l[q + 4*e];
        o0[4*e] = t0[e] + b2e + ph0[e];
        if (w1ok) o1[4*e] = t1[e] + b2e + ph1[e];
    }
}

extern "C" void kernel_launch(void* const* d_in, const int* in_sizes, int n_in,
                              void* d_out, int out_size, void* d_ws, size_t ws_size,
                              hipStream_t stream) {
    const float* f1   = (const float*)d_in[0];
    const float* f4   = (const float*)d_in[1];
    const float* fD   = (const float*)d_in[2];
    const float* Wp   = (const float*)d_in[3];
    const float* bp   = (const float*)d_in[4];
    const float* ln_g = (const float*)d_in[5];
    const float* ln_b = (const float*)d_in[6];
    const float* Wq   = (const float*)d_in[7];
    const float* bq   = (const float*)d_in[8];
    const float* Wk   = (const float*)d_in[9];
    const float* bk   = (const float*)d_in[10];
    const float* Wv   = (const float*)d_in[11];
    const float* bv   = (const float*)d_in[12];
    const float* Wo1  = (const float*)d_in[13];
    const float* bo1  = (const float*)d_in[14];
    const float* Wo2  = (const float*)d_in[15];
    const float* bo2  = (const float*)d_in[16];

    const int nRows  = in_sizes[0] / 256;
    const int blocks = (nRows + RPB - 1) / RPB;

    msfe_kernel<<<blocks, BLOCK, 0, stream>>>(
        f1, f4, fD, Wp, bp, ln_g, ln_b, Wq, bq, Wk, bk, Wv, bv,
        Wo1, bo1, Wo2, bo2, (float*)d_out, nRows);
}

// Round 2
// 288.788 us; speedup vs baseline: 1.2764x; 1.2574x over previous
//
#include <hip/hip_runtime.h>

#define BLOCK 512
#define RPB   128          // rows per block: 128 quads x 1 row
#define WPS   260          // Wp LDS row stride (floats): 260%32=4 -> quad lanes on distinct banks
#define WS    36           // 32x32 weight LDS row stride (floats): 36%32=4 -> conflict-free b128

#define DOT4(A_, W_) ((A_).x*(W_).x + (A_).y*(W_).y + (A_).z*(W_).z + (A_).w*(W_).w)

// out[d] = sum_j W[d][j]*in[j] for this lane's 8 outputs d = q+4e (full 32-dot via 4
// quad_perm phases). W stored with permuted columns: col j at (j&3)*8 + (j>>2), so the
// slice held by lane (q^p) (elements j = (q^p)+4j') is contiguous -> float4 reads.
__device__ __forceinline__ void matvec32(const float* __restrict__ WL, const int q,
                                         const float* __restrict__ in, float* __restrict__ outv)
{
    #pragma unroll
    for (int e = 0; e < 8; ++e) outv[e] = 0.f;
    #pragma unroll
    for (int p = 0; p < 4; ++p) {
        float xs[8];
        #pragma unroll
        for (int j = 0; j < 8; ++j)            // quad_perm DPP, compile-time mask
            xs[j] = (p == 0) ? in[j] : __shfl_xor(in[j], p);
        const float* wb = WL + q * WS + (q ^ p) * 8;
        #pragma unroll
        for (int e = 0; e < 8; ++e) {          // banks 4q+8(q^p)+16e -> distinct across quad
            float4 w0 = *(const float4*)(wb + e * (4 * WS));
            float4 w1 = *(const float4*)(wb + e * (4 * WS) + 4);
            outv[e] += w0.x*xs[0] + w0.y*xs[1] + w0.z*xs[2] + w0.w*xs[3]
                     + w1.x*xs[4] + w1.y*xs[5] + w1.z*xs[6] + w1.w*xs[7];
        }
    }
}

__launch_bounds__(BLOCK, 4)   // min 4 waves/EU -> VGPR cap 128; target natural ~80
__global__ void msfe_kernel(
    const float* __restrict__ f1, const float* __restrict__ f4, const float* __restrict__ fD,
    const float* __restrict__ Wp, const float* __restrict__ bp,
    const float* __restrict__ ln_g, const float* __restrict__ ln_b,
    const float* __restrict__ Wq, const float* __restrict__ bq,
    const float* __restrict__ Wk, const float* __restrict__ bk,
    const float* __restrict__ Wv, const float* __restrict__ bv,
    const float* __restrict__ Wo1, const float* __restrict__ bo1,
    const float* __restrict__ Wo2, const float* __restrict__ bo2,
    float* __restrict__ out, int nRows)
{
    __shared__ float Wp_l[32 * WPS];                       // 33.3 KB, padded stride
    __shared__ float A_l[32 * WS];                         // Wq^T Wk / sqrt(D), permuted cols
    __shared__ float Wv_l[32 * WS], Wo1_l[32 * WS], Wo2_l[32 * WS];  // permuted cols
    __shared__ float bp_l[32], g_l[32], b_l[32], u_l[32], v_l[32];
    __shared__ float bv_l[32], bo1_l[32], bo2_l[32];
    __shared__ float c_l;

    const int tid = threadIdx.x;
    const float isq = 0.17677669529663688f;  // 1/sqrt(32)

    // ---- stage Wp: [32][256] -> stride-260 rows (coalesced float4) ----
    #pragma unroll
    for (int i = 0; i < 4; ++i) {
        int idx = tid + i * BLOCK;                 // float4 index 0..2047
        int d = idx >> 6, k4 = idx & 63;
        *(float4*)&Wp_l[d * WPS + 4 * k4] = ((const float4*)Wp)[idx];
    }
    if (tid < 256) {
        // ---- stage Wv/Wo1/Wo2 with permuted columns: elem m of float4 j4 -> col' m*8+j4 ----
        int d = tid >> 3, j4 = tid & 7;
        float4 wv = ((const float4*)Wv )[tid];
        float4 w1 = ((const float4*)Wo1)[tid];
        float4 w2 = ((const float4*)Wo2)[tid];
        float* pv = &Wv_l [d * WS + j4];
        float* p1 = &Wo1_l[d * WS + j4];
        float* p2 = &Wo2_l[d * WS + j4];
        pv[0] = wv.x; pv[8] = wv.y; pv[16] = wv.z; pv[24] = wv.w;
        p1[0] = w1.x; p1[8] = w1.y; p1[16] = w1.z; p1[24] = w1.w;
        p2[0] = w2.x; p2[8] = w2.y; p2[16] = w2.z; p2[24] = w2.w;
        // ---- A = Wq^T Wk * isq (permuted cols), from global (L2-resident) ----
        int a = d, b4 = j4;
        float s0 = 0.f, s1 = 0.f, s2 = 0.f, s3 = 0.f;
        #pragma unroll 8
        for (int dd = 0; dd < 32; ++dd) {
            float  wq = Wq[dd * 32 + a];
            float4 wk = *(const float4*)&Wk[dd * 32 + 4 * b4];
            s0 += wq * wk.x; s1 += wq * wk.y; s2 += wq * wk.z; s3 += wq * wk.w;
        }
        float* pa = &A_l[a * WS + b4];
        pa[0] = s0 * isq; pa[8] = s1 * isq; pa[16] = s2 * isq; pa[24] = s3 * isq;
    } else if (tid < 288) {                        // u = (Wk^T bq) * isq
        int a = tid - 256; float s = 0.f;
        #pragma unroll 8
        for (int d = 0; d < 32; ++d) s += bq[d] * Wk[d * 32 + a];
        u_l[a] = s * isq;
    } else if (tid < 320) {                        // v = (Wq^T bk) * isq
        int a = tid - 288; float s = 0.f;
        #pragma unroll 8
        for (int d = 0; d < 32; ++d) s += Wq[d * 32 + a] * bk[d];
        v_l[a] = s * isq;
    } else if (tid == 320) {                       // c = bq.bk * isq
        float s = 0.f;
        #pragma unroll 8
        for (int d = 0; d < 32; ++d) s += bq[d] * bk[d];
        c_l = s * isq;
    } else if (tid >= 480) {
        int a = tid - 480;
        bp_l[a] = bp[a]; g_l[a] = ln_g[a]; b_l[a] = ln_b[a];
        // (only 32 lanes: tid 480..511)
    } else if (tid >= 448) {
        int a = tid - 448;
        bv_l[a] = bv[a]; bo1_l[a] = bo1[a]; bo2_l[a] = bo2[a];
    }
    __syncthreads();

    // ---- lane mapping: quad q owns interleaved outputs d = q + 4e; 1 row per quad ----
    const int q   = tid & 3;
    const int row = blockIdx.x * RPB + (tid >> 2);
    if (row >= nRows) return;                      // whole quad exits together

    const size_t rowoff = (size_t)row * 256;

    // ---- Phase A: per-stream full-K projection (8 outputs/lane), then ReLU+LN ----
    float Xh[3][8];
    #pragma unroll
    for (int s = 0; s < 3; ++s) {
        const float* __restrict__ px = (s == 0 ? f1 : s == 1 ? f4 : fD) + rowoff;
        float acc[8];
        #pragma unroll
        for (int e = 0; e < 8; ++e) acc[e] = 0.f;
        float4 xa = *(const float4*)(px);
        float4 xb = *(const float4*)(px + 4);
        #pragma unroll 1
        for (int kc = 0; kc < 256; kc += 8) {
            float4 ca = xa, cb = xb;
            const int kn = (kc + 8 < 256) ? kc + 8 : kc;   // last iter reloads (L1 hit)
            xa = *(const float4*)(px + kn);
            xb = *(const float4*)(px + kn + 4);
            const float* wr = &Wp_l[q * WPS + kc];
            #pragma unroll
            for (int e = 0; e < 8; ++e) {          // d = q+4e -> conflict-free, 16x broadcast
                float4 w0 = *(const float4*)(wr + e * (4 * WPS));
                float4 w1 = *(const float4*)(wr + e * (4 * WPS) + 4);
                acc[e] += DOT4(ca, w0) + DOT4(cb, w1);
            }
        }
        // bias + ReLU + LayerNorm (quad reduction over 32 dims)
        float sm = 0.f, sq = 0.f;
        #pragma unroll
        for (int e = 0; e < 8; ++e) {
            float t = fmaxf(acc[e] + bp_l[q + 4 * e], 0.f);
            acc[e] = t; sm += t; sq += t * t;
        }
        sm += __shfl_xor(sm, 1); sm += __shfl_xor(sm, 2);
        sq += __shfl_xor(sq, 1); sq += __shfl_xor(sq, 2);
        float mu  = sm * 0.03125f;
        float var = sq * 0.03125f - mu * mu;
        float inv = rsqrtf(var + 1e-5f);
        #pragma unroll
        for (int e = 0; e < 8; ++e)
            Xh[s][e] = g_l[q + 4 * e] * (acc[e] - mu) * inv + b_l[q + 4 * e];
    }

    // ---- scores sc[s][t] = X_s^T A X_t + u.X_t + v.X_s + c ----
    float uX[3], vX[3];
    #pragma unroll
    for (int t = 0; t < 3; ++t) {
        float us = 0.f, vs = 0.f;
        #pragma unroll
        for (int e = 0; e < 8; ++e) {
            us += u_l[q + 4 * e] * Xh[t][e];
            vs += v_l[q + 4 * e] * Xh[t][e];
        }
        us += __shfl_xor(us, 1); us += __shfl_xor(us, 2);
        vs += __shfl_xor(vs, 1); vs += __shfl_xor(vs, 2);
        uX[t] = us; vX[t] = vs;
    }

    float sc[9];
    #pragma unroll
    for (int t = 0; t < 3; ++t) {
        float y[8];
        matvec32(A_l, q, Xh[t], y);                // y[e] = (A X_t)[q+4e], full dot
        #pragma unroll
        for (int s = 0; s < 3; ++s) {
            float p = 0.f;
            #pragma unroll
            for (int e = 0; e < 8; ++e) p += Xh[s][e] * y[e];
            sc[s * 3 + t] = p;                     // partial over my 8 dims
        }
    }
    #pragma unroll
    for (int s = 0; s < 3; ++s)
        #pragma unroll
        for (int t = 0; t < 3; ++t) {
            float p = sc[s * 3 + t];
            p += __shfl_xor(p, 1); p += __shfl_xor(p, 2);
            sc[s * 3 + t] = p + uX[t] + vX[s] + c_l;
        }

    // ---- softmax rows; fold V through xb = sum_t g_t X_t (rows sum to 1 -> bias folds) ----
    float g0 = 0.f, g1 = 0.f, g2 = 0.f;
    #pragma unroll
    for (int s = 0; s < 3; ++s) {
        float a0 = sc[s*3+0], a1 = sc[s*3+1], a2 = sc[s*3+2];
        float m  = fmaxf(a0, fmaxf(a1, a2));
        float e0 = __expf(a0 - m), e1 = __expf(a1 - m), e2 = __expf(a2 - m);
        float r  = 1.f / (e0 + e1 + e2);
        g0 += e0 * r; g1 += e1 * r; g2 += e2 * r;
    }
    g0 *= (1.f/3.f); g1 *= (1.f/3.f); g2 *= (1.f/3.f);

    float xb[8];
    #pragma unroll
    for (int e = 0; e < 8; ++e)
        xb[e] = g0 * Xh[0][e] + g1 * Xh[1][e] + g2 * Xh[2][e];

    // ---- pooled = Wv xb + bv ; h1 = relu(Wo1 pooled + bo1) ; out = Wo2 h1 + bo2 + pooled ----
    float t8[8], ph[8], hh[8];
    matvec32(Wv_l, q, xb, t8);
    #pragma unroll
    for (int e = 0; e < 8; ++e) ph[e] = t8[e] + bv_l[q + 4 * e];
    matvec32(Wo1_l, q, ph, t8);
    #pragma unroll
    for (int e = 0; e < 8; ++e) hh[e] = fmaxf(t8[e] + bo1_l[q + 4 * e], 0.f);
    matvec32(Wo2_l, q, hh, t8);

    float* o = out + (size_t)row * 32 + q;
    #pragma unroll
    for (int e = 0; e < 8; ++e)
        o[4 * e] = t8[e] + bo2_l[q + 4 * e] + ph[e];
}

extern "C" void kernel_launch(void* const* d_in, const int* in_sizes, int n_in,
                              void* d_out, int out_size, void* d_ws, size_t ws_size,
                              hipStream_t stream) {
    const float* f1   = (const float*)d_in[0];
    const float* f4   = (const float*)d_in[1];
    const float* fD   = (const float*)d_in[2];
    const float* Wp   = (const float*)d_in[3];
    const float* bp   = (const float*)d_in[4];
    const float* ln_g = (const float*)d_in[5];
    const float* ln_b = (const float*)d_in[6];
    const float* Wq   = (const float*)d_in[7];
    const float* bq   = (const float*)d_in[8];
    const float* Wk   = (const float*)d_in[9];
    const float* bk   = (const float*)d_in[10];
    const float* Wv   = (const float*)d_in[11];
    const float* bv   = (const float*)d_in[12];
    const float* Wo1  = (const float*)d_in[13];
    const float* bo1  = (const float*)d_in[14];
    const float* Wo2  = (const float*)d_in[15];
    const float* bo2  = (const float*)d_in[16];

    const int nRows  = in_sizes[0] / 256;
    const int blocks = (nRows + RPB - 1) / RPB;

    msfe_kernel<<<blocks, BLOCK, 0, stream>>>(
        f1, f4, fD, Wp, bp, ln_g, ln_b, Wq, bq, Wk, bk, Wv, bv,
        Wo1, bo1, Wo2, bo2, (float*)d_out, nRows);
}

// Round 3
// 274.979 us; speedup vs baseline: 1.3405x; 1.0502x over previous
//
#include <hip/hip_runtime.h>

#define BLOCK 512
#define RPB   128          // rows per block: 128 quads x 1 row
#define WPS   260          // Wp LDS row stride (floats): 260%32=4 -> quad lanes on distinct banks
#define WS    36           // 32x32 weight LDS row stride (floats): 36%32=4 -> conflict-free b128

#define DOT4(A_, W_) ((A_).x*(W_).x + (A_).y*(W_).y + (A_).z*(W_).z + (A_).w*(W_).w)

// out[d] = sum_j W[d][j]*in[j] for this lane's 8 outputs d = q+4e (full 32-dot via 4
// quad_perm phases). W stored with permuted columns: col j at (j&3)*8 + (j>>2), so the
// slice held by lane (q^p) (elements j = (q^p)+4j') is contiguous -> float4 reads.
__device__ __forceinline__ void matvec32(const float* __restrict__ WL, const int q,
                                         const float* __restrict__ in, float* __restrict__ outv)
{
    #pragma unroll
    for (int e = 0; e < 8; ++e) outv[e] = 0.f;
    #pragma unroll
    for (int p = 0; p < 4; ++p) {
        float xs[8];
        #pragma unroll
        for (int j = 0; j < 8; ++j)            // quad_perm DPP, compile-time mask
            xs[j] = (p == 0) ? in[j] : __shfl_xor(in[j], p);
        const float* wb = WL + q * WS + (q ^ p) * 8;
        #pragma unroll
        for (int e = 0; e < 8; ++e) {          // banks 4q+8(q^p)+16e -> distinct across quad
            float4 w0 = *(const float4*)(wb + e * (4 * WS));
            float4 w1 = *(const float4*)(wb + e * (4 * WS) + 4);
            outv[e] += w0.x*xs[0] + w0.y*xs[1] + w0.z*xs[2] + w0.w*xs[3]
                     + w1.x*xs[4] + w1.y*xs[5] + w1.z*xs[6] + w1.w*xs[7];
        }
    }
}

__launch_bounds__(BLOCK, 4)   // 4 waves/EU -> VGPR cap 128
__global__ void msfe_kernel(
    const float* __restrict__ f1, const float* __restrict__ f4, const float* __restrict__ fD,
    const float* __restrict__ Wp, const float* __restrict__ bp,
    const float* __restrict__ ln_g, const float* __restrict__ ln_b,
    const float* __restrict__ Wq, const float* __restrict__ bq,
    const float* __restrict__ Wk, const float* __restrict__ bk,
    const float* __restrict__ Wv, const float* __restrict__ bv,
    const float* __restrict__ Wo1, const float* __restrict__ bo1,
    const float* __restrict__ Wo2, const float* __restrict__ bo2,
    float* __restrict__ out, int nRows)
{
    __shared__ float Wp_l[32 * WPS];                       // 33.3 KB, padded stride
    __shared__ float A_l[32 * WS];                         // Wq^T Wk / sqrt(D), permuted cols
    __shared__ float Wv_l[32 * WS], Wo1_l[32 * WS], Wo2_l[32 * WS];  // permuted cols
    __shared__ float bp_l[32], g_l[32], b_l[32], u_l[32], v_l[32];
    __shared__ float bv_l[32], bo1_l[32], bo2_l[32];
    __shared__ float c_l;

    const int tid = threadIdx.x;
    const float isq = 0.17677669529663688f;  // 1/sqrt(32)

    // ---- stage Wp: [32][256] -> stride-260 rows (coalesced float4) ----
    #pragma unroll
    for (int i = 0; i < 4; ++i) {
        int idx = tid + i * BLOCK;                 // float4 index 0..2047
        int d = idx >> 6, k4 = idx & 63;
        *(float4*)&Wp_l[d * WPS + 4 * k4] = ((const float4*)Wp)[idx];
    }
    if (tid < 256) {
        // ---- stage Wv/Wo1/Wo2 with permuted columns: elem m of float4 j4 -> col' m*8+j4 ----
        int d = tid >> 3, j4 = tid & 7;
        float4 wv = ((const float4*)Wv )[tid];
        float4 w1 = ((const float4*)Wo1)[tid];
        float4 w2 = ((const float4*)Wo2)[tid];
        float* pv = &Wv_l [d * WS + j4];
        float* p1 = &Wo1_l[d * WS + j4];
        float* p2 = &Wo2_l[d * WS + j4];
        pv[0] = wv.x; pv[8] = wv.y; pv[16] = wv.z; pv[24] = wv.w;
        p1[0] = w1.x; p1[8] = w1.y; p1[16] = w1.z; p1[24] = w1.w;
        p2[0] = w2.x; p2[8] = w2.y; p2[16] = w2.z; p2[24] = w2.w;
        // ---- A = Wq^T Wk * isq (permuted cols), from global (L2-resident) ----
        int a = d, b4 = j4;
        float s0 = 0.f, s1 = 0.f, s2 = 0.f, s3 = 0.f;
        #pragma unroll 8
        for (int dd = 0; dd < 32; ++dd) {
            float  wq = Wq[dd * 32 + a];
            float4 wk = *(const float4*)&Wk[dd * 32 + 4 * b4];
            s0 += wq * wk.x; s1 += wq * wk.y; s2 += wq * wk.z; s3 += wq * wk.w;
        }
        float* pa = &A_l[a * WS + b4];
        pa[0] = s0 * isq; pa[8] = s1 * isq; pa[16] = s2 * isq; pa[24] = s3 * isq;
    } else if (tid < 288) {                        // u = (Wk^T bq) * isq
        int a = tid - 256; float s = 0.f;
        #pragma unroll 8
        for (int d = 0; d < 32; ++d) s += bq[d] * Wk[d * 32 + a];
        u_l[a] = s * isq;
    } else if (tid < 320) {                        // v = (Wq^T bk) * isq
        int a = tid - 288; float s = 0.f;
        #pragma unroll 8
        for (int d = 0; d < 32; ++d) s += Wq[d * 32 + a] * bk[d];
        v_l[a] = s * isq;
    } else if (tid == 320) {                       // c = bq.bk * isq
        float s = 0.f;
        #pragma unroll 8
        for (int d = 0; d < 32; ++d) s += bq[d] * bk[d];
        c_l = s * isq;
    } else if (tid >= 480) {
        int a = tid - 480;
        bp_l[a] = bp[a]; g_l[a] = ln_g[a]; b_l[a] = ln_b[a];
    } else if (tid >= 448) {
        int a = tid - 448;
        bv_l[a] = bv[a]; bo1_l[a] = bo1[a]; bo2_l[a] = bo2[a];
    }
    __syncthreads();

    // ---- lane mapping: quad q owns interleaved outputs d = q + 4e; 1 row per quad ----
    const int q   = tid & 3;
    const int row = blockIdx.x * RPB + (tid >> 2);
    if (row >= nRows) return;                      // whole quad exits together

    const size_t rowoff = (size_t)row * 256;
    const float* __restrict__ p0 = f1 + rowoff;
    const float* __restrict__ p1 = f4 + rowoff;
    const float* __restrict__ p2 = fD + rowoff;

    // ---- Phase A: fused 3-stream full-K projection (each weight read feeds 24 FMAs) ----
    float acc0[8], acc1[8], acc2[8];
    #pragma unroll
    for (int e = 0; e < 8; ++e) { acc0[e] = 0.f; acc1[e] = 0.f; acc2[e] = 0.f; }

    float4 n0a = *(const float4*)(p0), n0b = *(const float4*)(p0 + 4);
    float4 n1a = *(const float4*)(p1), n1b = *(const float4*)(p1 + 4);
    float4 n2a = *(const float4*)(p2), n2b = *(const float4*)(p2 + 4);

    const float* wbase = &Wp_l[q * WPS];

    #pragma unroll 1
    for (int kc = 0; kc < 256; kc += 8) {
        float4 c0a = n0a, c0b = n0b, c1a = n1a, c1b = n1b, c2a = n2a, c2b = n2b;
        const int kn = (kc + 8 < 256) ? kc + 8 : kc;   // last iter reloads (L1 hit)
        n0a = *(const float4*)(p0 + kn); n0b = *(const float4*)(p0 + kn + 4);
        n1a = *(const float4*)(p1 + kn); n1b = *(const float4*)(p1 + kn + 4);
        n2a = *(const float4*)(p2 + kn); n2b = *(const float4*)(p2 + kn + 4);
        const float* wr = wbase + kc;
        #pragma unroll
        for (int e = 0; e < 8; ++e) {              // d = q+4e -> conflict-free, 16x broadcast
            float4 w0 = *(const float4*)(wr + e * (4 * WPS));
            float4 w1 = *(const float4*)(wr + e * (4 * WPS) + 4);
            acc0[e] += DOT4(c0a, w0) + DOT4(c0b, w1);
            acc1[e] += DOT4(c1a, w0) + DOT4(c1b, w1);
            acc2[e] += DOT4(c2a, w0) + DOT4(c2b, w1);
        }
    }

    // ---- bias + ReLU + LayerNorm per stream (quad reduction over 32 dims) ----
    float Xh[3][8];
    float bpe[8], ge[8], be[8];
    #pragma unroll
    for (int e = 0; e < 8; ++e) { bpe[e] = bp_l[q + 4*e]; ge[e] = g_l[q + 4*e]; be[e] = b_l[q + 4*e]; }
    #pragma unroll
    for (int s = 0; s < 3; ++s) {
        float* accp = (s == 0) ? acc0 : (s == 1) ? acc1 : acc2;
        float sm = 0.f, sq = 0.f;
        #pragma unroll
        for (int e = 0; e < 8; ++e) {
            float t = fmaxf(accp[e] + bpe[e], 0.f);
            accp[e] = t; sm += t; sq += t * t;
        }
        sm += __shfl_xor(sm, 1); sm += __shfl_xor(sm, 2);
        sq += __shfl_xor(sq, 1); sq += __shfl_xor(sq, 2);
        float mu  = sm * 0.03125f;
        float var = sq * 0.03125f - mu * mu;
        float inv = rsqrtf(var + 1e-5f);
        #pragma unroll
        for (int e = 0; e < 8; ++e)
            Xh[s][e] = ge[e] * (accp[e] - mu) * inv + be[e];
    }

    // ---- scores sc[s][t] = X_s^T A X_t + u.X_t + v.X_s + c ----
    float uX[3], vX[3];
    {
        float uq[8], vq[8];
        #pragma unroll
        for (int e = 0; e < 8; ++e) { uq[e] = u_l[q + 4*e]; vq[e] = v_l[q + 4*e]; }
        #pragma unroll
        for (int t = 0; t < 3; ++t) {
            float us = 0.f, vs = 0.f;
            #pragma unroll
            for (int e = 0; e < 8; ++e) { us += uq[e] * Xh[t][e]; vs += vq[e] * Xh[t][e]; }
            us += __shfl_xor(us, 1); us += __shfl_xor(us, 2);
            vs += __shfl_xor(vs, 1); vs += __shfl_xor(vs, 2);
            uX[t] = us; vX[t] = vs;
        }
    }

    float sc[9];
    #pragma unroll
    for (int t = 0; t < 3; ++t) {
        float y[8];
        matvec32(A_l, q, Xh[t], y);                // y[e] = (A X_t)[q+4e], full dot
        #pragma unroll
        for (int s = 0; s < 3; ++s) {
            float p = 0.f;
            #pragma unroll
            for (int e = 0; e < 8; ++e) p += Xh[s][e] * y[e];
            sc[s * 3 + t] = p;                     // partial over my 8 dims
        }
    }
    #pragma unroll
    for (int s = 0; s < 3; ++s)
        #pragma unroll
        for (int t = 0; t < 3; ++t) {
            float p = sc[s * 3 + t];
            p += __shfl_xor(p, 1); p += __shfl_xor(p, 2);
            sc[s * 3 + t] = p + uX[t] + vX[s] + c_l;
        }

    // ---- softmax rows; fold V through xb = sum_t g_t X_t (rows sum to 1 -> bias folds) ----
    float g0 = 0.f, g1 = 0.f, g2 = 0.f;
    #pragma unroll
    for (int s = 0; s < 3; ++s) {
        float a0 = sc[s*3+0], a1 = sc[s*3+1], a2 = sc[s*3+2];
        float m  = fmaxf(a0, fmaxf(a1, a2));
        float e0 = __expf(a0 - m), e1 = __expf(a1 - m), e2 = __expf(a2 - m);
        float r  = 1.f / (e0 + e1 + e2);
        g0 += e0 * r; g1 += e1 * r; g2 += e2 * r;
    }
    g0 *= (1.f/3.f); g1 *= (1.f/3.f); g2 *= (1.f/3.f);

    float xb[8];
    #pragma unroll
    for (int e = 0; e < 8; ++e)
        xb[e] = g0 * Xh[0][e] + g1 * Xh[1][e] + g2 * Xh[2][e];

    // ---- pooled = Wv xb + bv ; h1 = relu(Wo1 pooled + bo1) ; out = Wo2 h1 + bo2 + pooled ----
    float t8[8], ph[8], hh[8];
    matvec32(Wv_l, q, xb, t8);
    #pragma unroll
    for (int e = 0; e < 8; ++e) ph[e] = t8[e] + bv_l[q + 4 * e];
    matvec32(Wo1_l, q, ph, t8);
    #pragma unroll
    for (int e = 0; e < 8; ++e) hh[e] = fmaxf(t8[e] + bo1_l[q + 4 * e], 0.f);
    matvec32(Wo2_l, q, hh, t8);

    float* o = out + (size_t)row * 32 + q;
    #pragma unroll
    for (int e = 0; e < 8; ++e)
        o[4 * e] = t8[e] + bo2_l[q + 4 * e] + ph[e];
}

extern "C" void kernel_launch(void* const* d_in, const int* in_sizes, int n_in,
                              void* d_out, int out_size, void* d_ws, size_t ws_size,
                              hipStream_t stream) {
    const float* f1   = (const float*)d_in[0];
    const float* f4   = (const float*)d_in[1];
    const float* fD   = (const float*)d_in[2];
    const float* Wp   = (const float*)d_in[3];
    const float* bp   = (const float*)d_in[4];
    const float* ln_g = (const float*)d_in[5];
    const float* ln_b = (const float*)d_in[6];
    const float* Wq   = (const float*)d_in[7];
    const float* bq   = (const float*)d_in[8];
    const float* Wk   = (const float*)d_in[9];
    const float* bk   = (const float*)d_in[10];
    const float* Wv   = (const float*)d_in[11];
    const float* bv   = (const float*)d_in[12];
    const float* Wo1  = (const float*)d_in[13];
    const float* bo1  = (const float*)d_in[14];
    const float* Wo2  = (const float*)d_in[15];
    const float* bo2  = (const float*)d_in[16];

    const int nRows  = in_sizes[0] / 256;
    const int blocks = (nRows + RPB - 1) / RPB;

    msfe_kernel<<<blocks, BLOCK, 0, stream>>>(
        f1, f4, fD, Wp, bp, ln_g, ln_b, Wq, bq, Wk, bk, Wv, bv,
        Wo1, bo1, Wo2, bo2, (float*)d_out, nRows);
}